// Round 1
// baseline (270.482 us; speedup 1.0000x reference)
//
#include <hip/hip_runtime.h>

// Frobenius — R10: 256x256 tile ownership, ONE rendezvous per iteration.
//
// R9 (181 us kernel) was rendezvous-bound: 16-row-band ownership forces every
// block to need all 4096 col sums -> a 256-way reduction aggregated via TWO
// flag-ordered cross-XCD rounds per iter, plus 4 MB/iter of colpart atomics
// (2x sector-amplified -> WRITE_SIZE 230 MB).
//
// R10 retiles X into 256x256 tiles: block (bi,bj) = b>>4,b&15; thread t
// (c=t&63, g=t>>6) holds rows bi*256+16g..+15, cols bj*256+4c..4c+3 (same 64
// VGPRs). Now a block needs only:
//   colsum(256 cols) = fold of 16 peers' colpart[256]  (column band, bi'=0..15)
//   rowsum(256 rows) = fold of 16 peers' rowpart[256]  (row band,    bj'=0..15)
//   s                = fold of 256 per-block scalars (packed into the flag)
// Publish = 2 KB/block/iter (0.53 MB device-wide, was 4 MB), consumers fold
// locally -> the second rendezvous disappears.
//
// Sync (proven primitives only):
//  - ALL cross-block data via b64 relaxed agent atomics (R8 lesson).
//  - writer: data stores -> s_waitcnt vmcnt(0) -> __syncthreads -> t0 flag
//    (tag|blocksum packed in one b64)  [R5-R9 pattern].
//  - parity (iter&1) double-buffered data + flags; exact-tag polls -> data
//    arrays need no init (poison/replay safe); memset only flags+rdg (4.3 KB).
//  - WAR: block t0 bumps rdg[parity][bi] after its reads (post-B1 barrier);
//    writers gate parity-p stores of iter k on rdg[p][*] >= 16*(k>>1), i.e.
//    all 256 blocks finished reading iter k-2. Gate checked at loop top,
//    ~1 full iteration stale -> almost always already satisfied.

#define NN    4096
#define NV4   1024
#define NBLK  256
#define ITERS 20
#define INV_N (1.0f / 4096.0f)

typedef unsigned long long u64;
typedef float f32x4 __attribute__((ext_vector_type(4)));

__device__ __forceinline__ float wave_reduce_sum(float v) {
    #pragma unroll
    for (int m = 1; m < 64; m <<= 1) v += __shfl_xor(v, m, 64);
    return v;
}
__device__ __forceinline__ void st_b64(u64* p, u64 v) {
    __hip_atomic_store(p, v, __ATOMIC_RELAXED, __HIP_MEMORY_SCOPE_AGENT);
}
__device__ __forceinline__ u64 ld_b64(const u64* p) {
    return __hip_atomic_load(p, __ATOMIC_RELAXED, __HIP_MEMORY_SCOPE_AGENT);
}
__device__ __forceinline__ u64 packf2(float a, float b) {
    return (u64)__float_as_uint(a) | ((u64)__float_as_uint(b) << 32);
}
__device__ __forceinline__ float lo32(u64 u) { return __uint_as_float((unsigned)u); }
__device__ __forceinline__ float hi32(u64 u) { return __uint_as_float((unsigned)(u >> 32)); }

__global__ __launch_bounds__(1024, 4)
void persist9(const float* __restrict__ X0, float* __restrict__ Xout,
              u64* __restrict__ colF,    // [2][256][128] b64 = 2 packed f32
              u64* __restrict__ rowF,    // [2][256][128]
              u64* __restrict__ pflag,   // [2][256]  (tag<<32 | blocksum bits)
              u64* __restrict__ rdg)     // [2][16]   read-group counters
{
    const int t    = threadIdx.x;
    const int lane = t & 63;
    const int g    = t >> 6;          // wave = 16-row group
    const int c    = lane;            // 4-col quad
    const int b    = blockIdx.x;
    const int bi   = b >> 4;
    const int bj   = b & 15;

    // ~105.5 KB total -> 1 block/CU guaranteed (grid == 256 == #CUs).
    __shared__ float part[16][64][17];   // row-partial transpose (69.6 KB)
    __shared__ f32x4 cq[16][64];         // col partials (A) / col gathers (B)
    __shared__ f32x4 rq4[16][64];        // row gathers (B)
    __shared__ float bsv[256];           // peer blocksums
    __shared__ f32x4 colq[64];           // final colsum quads
    __shared__ float rsum[256];          // final rowsums
    __shared__ float sG;                 // grand total

    f32x4 x[16];
    {
        const f32x4* xi = (const f32x4*)X0;
        const size_t base = (size_t)(bi * 256 + g * 16) * NV4 + (bj * 64 + c);
        #pragma unroll
        for (int r = 0; r < 16; ++r)
            x[r] = xi[base + (size_t)r * NV4];
    }

    for (int iter = 0; iter < ITERS; ++iter) {
        const int p = iter & 1;
        const u64 tagv = (u64)(iter + 1);

        // ---- WAR gate: parity-p buffers are free once all 256 blocks have
        //      read iter-2's data. Bumps happened a full iteration ago.
        if (iter >= 2) {
            if (lane < 16) {
                const u64 need = (u64)16 * (u64)(iter >> 1);
                const u64* f = rdg + (p * 16 + lane);
                while (ld_b64(f) < need) __builtin_amdgcn_s_sleep(1);
            }
            asm volatile("" ::: "memory");
        }

        // ---- phase A: local folds + publish (2 KB/block)
        f32x4 cacc = x[0];
        #pragma unroll
        for (int r = 1; r < 16; ++r) cacc += x[r];
        cq[g][c] = cacc;                              // per-wave col partial
        #pragma unroll
        for (int r = 0; r < 16; ++r)                  // bank-safe (17 pad)
            part[g][c][r] = (x[r].x + x[r].y) + (x[r].z + x[r].w);
        __syncthreads();                              // A1

        float bs = 0.f;
        if (g == 0) {   // fold 16 waves' col partials, publish 256 cols
            f32x4 v = cq[0][c];
            #pragma unroll
            for (int k = 1; k < 16; ++k) v += cq[k][c];
            u64* dst = colF + (((size_t)(p * NBLK + b)) << 7) + 2 * c;
            st_b64(dst,     packf2(v.x, v.y));
            st_b64(dst + 1, packf2(v.z, v.w));
            bs = wave_reduce_sum((v.x + v.y) + (v.z + v.w));   // blocksum
        }
        {   // row fold: this wave's 16 rows over 64 col-quads (LDS transpose)
            const int r = lane & 15, q = lane >> 4;
            float v = 0.f;
            #pragma unroll
            for (int k = 0; k < 16; ++k) v += part[g][q * 16 + k][r];
            v += __shfl_xor(v, 16, 64);
            v += __shfl_xor(v, 32, 64);
            float vp = __shfl_xor(v, 1, 64);          // partner row value
            if (lane < 16 && (lane & 1) == 0) {       // 8 b64 per wave
                u64* dst = rowF + (((size_t)(p * NBLK + b)) << 7) + 8 * g + (lane >> 1);
                st_b64(dst, packf2(v, vp));
            }
        }
        asm volatile("s_waitcnt vmcnt(0)" ::: "memory");  // own stores acked
        __syncthreads();                                  // A2: all drained
        if (t == 0)
            st_b64(pflag + (p * NBLK + b),
                   (tagv << 32) | (u64)__float_as_uint(bs));

        // ---- phase B: poll 2-3 flags, gather 4 b64, fold locally
        const int fcsrc = g * 16 + bj;    // col source block (bi'=g, bj)
        const int frsrc = bi * 16 + g;    // row source block (bi, bj'=g)
        {
            const u64* fc = pflag + (p * NBLK + fcsrc);
            const u64* fr = pflag + (p * NBLK + frsrc);
            const u64* fb = pflag + (p * NBLK + (t & 255));
            bool dc = false, dr = false, db = (t >= 256);
            u64 ub = 0;
            while (true) {
                if (!dc && (ld_b64(fc) >> 32) == tagv) dc = true;
                if (!dr && (ld_b64(fr) >> 32) == tagv) dr = true;
                if (!db) { u64 u = ld_b64(fb);
                           if ((u >> 32) == tagv) { ub = u; db = true; } }
                if (dc && dr && db) break;
                __builtin_amdgcn_s_sleep(1);
            }
            if (t < 256) bsv[t] = lo32(ub);
        }
        asm volatile("" ::: "memory");    // no hoisting loads above polls
        {
            const u64* cp = colF + (((size_t)(p * NBLK + fcsrc)) << 7) + 2 * c;
            const u64* rp = rowF + (((size_t)(p * NBLK + frsrc)) << 7) + 2 * c;
            u64 c0 = ld_b64(cp), c1 = ld_b64(cp + 1);
            u64 r0 = ld_b64(rp), r1 = ld_b64(rp + 1);
            f32x4 cv, rv;
            cv.x = lo32(c0); cv.y = hi32(c0); cv.z = lo32(c1); cv.w = hi32(c1);
            rv.x = lo32(r0); rv.y = hi32(r0); rv.z = lo32(r1); rv.w = hi32(r1);
            cq[g][c]  = cv;               // cols 4c..4c+3 from peer g
            rq4[g][c] = rv;               // rows 4c..4c+3 from peer g
        }
        __syncthreads();                                  // B1: reads done
        if (t == 0)   // unblock writers of iter+2 (same parity)
            __hip_atomic_fetch_add(rdg + (p * 16 + bi), (u64)1,
                                   __ATOMIC_RELAXED, __HIP_MEMORY_SCOPE_AGENT);
        if (g == 0) {            // colsum: fold 16 peer partials
            f32x4 v = cq[0][c];
            #pragma unroll
            for (int k = 1; k < 16; ++k) v += cq[k][c];
            colq[c] = v;
        } else if (g >= 4 && g < 8) {   // rowsum: 256 rows, conflict-free
            const int row = t - 256;
            const float* rqf = (const float*)rq4;
            float v = 0.f;
            #pragma unroll
            for (int k = 0; k < 16; ++k) v += rqf[k * 256 + row];
            rsum[row] = v;
        } else if (g == 8) {            // grand total (identical all blocks)
            float v = bsv[lane] + bsv[64 + lane] + bsv[128 + lane] + bsv[192 + lane];
            v = wave_reduce_sum(v);
            if (lane == 0) sG = v;
        }
        __syncthreads();                                  // B2

        const float cc0 = INV_N + sG * (INV_N * INV_N);
        const f32x4 csub = colq[c] * INV_N;
        #pragma unroll
        for (int r = 0; r < 16; ++r) {
            const float a = cc0 - rsum[g * 16 + r] * INV_N;
            x[r].x = fmaxf(x[r].x + a - csub.x, 0.f);
            x[r].y = fmaxf(x[r].y + a - csub.y, 0.f);
            x[r].z = fmaxf(x[r].z + a - csub.z, 0.f);
            x[r].w = fmaxf(x[r].w + a - csub.w, 0.f);
        }
    }

    {   // final store (plain cached path)
        f32x4* xo = (f32x4*)Xout;
        const size_t base = (size_t)(bi * 256 + g * 16) * NV4 + (bj * 64 + c);
        #pragma unroll
        for (int r = 0; r < 16; ++r)
            xo[base + (size_t)r * NV4] = x[r];
    }
}

extern "C" void kernel_launch(void* const* d_in, const int* in_sizes, int n_in,
                              void* d_out, int out_size, void* d_ws, size_t ws_size,
                              hipStream_t stream)
{
    const float* X0 = (const float*)d_in[0];
    float* X = (float*)d_out;

    // ws: colF 512 KB | rowF 512 KB | pflag 4 KB | rdg 256 B   (~1.03 MB)
    u64* colF  = (u64*)d_ws;
    u64* rowF  = colF + 2 * NBLK * 128;
    u64* pflag = rowF + 2 * NBLK * 128;
    u64* rdg   = pflag + 2 * NBLK;

    // Only flags + read-counters need zeroing (data polls are exact-tag,
    // so poisoned/stale data words can never satisfy a poll).
    hipMemsetAsync((void*)pflag, 0, (2 * NBLK + 2 * 16) * sizeof(u64), stream);

    // 105.5 KB LDS + 16 waves -> exactly 1 block/CU; grid == CU count ->
    // all 256 blocks co-resident (spin-waits are deadlock-free).
    persist9<<<dim3(NBLK), dim3(1024), 0, stream>>>(X0, X, colF, rowF,
                                                    pflag, rdg);
}

// Round 2
// 250.128 us; speedup vs baseline: 1.0814x; 1.0814x over previous
//
#include <hip/hip_runtime.h>

// Frobenius — R11: R10 dataflow (256x256 tiles, ONE rendezvous/iter) with
// R9's proven rendezvous mechanics restored.
//
// R10 post-mortem: WRITE_SIZE fell 230->102 MB as predicted but dur_us was
// flat (181->188 us) at 7% HBM -> purely latency-bound. R10's rendezvous
// itself got 2x slower than R9's (8.5 vs 4.4 us/round), cancelling the
// halved round count. Two self-inflicted wounds:
//   (a) flags packed 8-per-64B-line (R9 spaced them 64 B apart) -> every
//       flag store contends with remote polls of 7 unrelated flags;
//   (b) ALL 1024 threads polled 3 flags each (786K device-wide poll streams
//       of agent-scope atomic loads) vs R9's 256/block -> fabric congestion
//       delays the very flag stores being polled.
//
// R11 changes (dataflow identical to R10):
//   - pflag spaced 64 B apart (stride-8 u64), parity-doubled.
//   - exactly 256 pollers/block: thread t<256 polls block t's flag (one
//     poller per flag per block, R9's density), captures the blocksum
//     payload to LDS; everyone else sleeps at the barrier. After that
//     barrier ALL flags are known set -> col/row gathers need no wait.
//   - rdg WAR gate DELETED: the per-iter full barrier (all 256 flags
//     observed at tag k) transitively orders iter-k writes after all
//     iter-(k-2) reads: any block entering iter k saw every block's flag
//     at k-1, which each block stores only after finishing its k-2 reads.
//
// Sync primitives unchanged (R5-R10 proven): all cross-block data via b64
// relaxed agent atomics; writer = data stores -> s_waitcnt vmcnt(0) ->
// __syncthreads -> t0 flag (tag<<32 | blocksum bits); exact-tag polls ->
// data arrays need no init (poison/replay safe); memset only pflag (32 KB).

#define NN    4096
#define NV4   1024
#define NBLK  256
#define ITERS 20
#define INV_N (1.0f / 4096.0f)

typedef unsigned long long u64;
typedef float f32x4 __attribute__((ext_vector_type(4)));

__device__ __forceinline__ float wave_reduce_sum(float v) {
    #pragma unroll
    for (int m = 1; m < 64; m <<= 1) v += __shfl_xor(v, m, 64);
    return v;
}
__device__ __forceinline__ void st_b64(u64* p, u64 v) {
    __hip_atomic_store(p, v, __ATOMIC_RELAXED, __HIP_MEMORY_SCOPE_AGENT);
}
__device__ __forceinline__ u64 ld_b64(const u64* p) {
    return __hip_atomic_load(p, __ATOMIC_RELAXED, __HIP_MEMORY_SCOPE_AGENT);
}
__device__ __forceinline__ u64 packf2(float a, float b) {
    return (u64)__float_as_uint(a) | ((u64)__float_as_uint(b) << 32);
}
__device__ __forceinline__ float lo32(u64 u) { return __uint_as_float((unsigned)u); }
__device__ __forceinline__ float hi32(u64 u) { return __uint_as_float((unsigned)(u >> 32)); }

__global__ __launch_bounds__(1024, 4)
void persist10(const float* __restrict__ X0, float* __restrict__ Xout,
               u64* __restrict__ colF,    // [2][256][128] b64 = 2 packed f32
               u64* __restrict__ rowF,    // [2][256][128]
               u64* __restrict__ pflag)   // [2][256] stride-8 u64 (64 B apart)
{
    const int t    = threadIdx.x;
    const int lane = t & 63;
    const int g    = t >> 6;          // wave = 16-row group
    const int c    = lane;            // 4-col quad
    const int b    = blockIdx.x;
    const int bi   = b >> 4;
    const int bj   = b & 15;

    // ~103.5 KB total -> 1 block/CU guaranteed (grid == 256 == #CUs).
    __shared__ float part[16][64][17];   // row-partial transpose (69.6 KB)
    __shared__ f32x4 cq[16][64];         // col partials (A) / col gathers (B)
    __shared__ f32x4 rq4[16][64];        // row gathers (B)
    __shared__ float bsv[256];           // peer blocksums (from flag payload)
    __shared__ f32x4 colq[64];           // final colsum quads
    __shared__ float rsum[256];          // final rowsums
    __shared__ float sG;                 // grand total

    f32x4 x[16];
    {
        const f32x4* xi = (const f32x4*)X0;
        const size_t base = (size_t)(bi * 256 + g * 16) * NV4 + (bj * 64 + c);
        #pragma unroll
        for (int r = 0; r < 16; ++r)
            x[r] = xi[base + (size_t)r * NV4];
    }

    for (int iter = 0; iter < ITERS; ++iter) {
        const int p = iter & 1;
        const u64 tagv = (u64)(iter + 1);

        // ---- phase A: local folds + publish (2 KB/block)
        f32x4 cacc = x[0];
        #pragma unroll
        for (int r = 1; r < 16; ++r) cacc += x[r];
        cq[g][c] = cacc;                              // per-wave col partial
        #pragma unroll
        for (int r = 0; r < 16; ++r)                  // bank-safe (17 pad)
            part[g][c][r] = (x[r].x + x[r].y) + (x[r].z + x[r].w);
        __syncthreads();                              // A1

        float bs = 0.f;
        if (g == 0) {   // fold 16 waves' col partials, publish 256 cols
            f32x4 v = cq[0][c];
            #pragma unroll
            for (int k = 1; k < 16; ++k) v += cq[k][c];
            u64* dst = colF + (((size_t)(p * NBLK + b)) << 7) + 2 * c;
            st_b64(dst,     packf2(v.x, v.y));
            st_b64(dst + 1, packf2(v.z, v.w));
            bs = wave_reduce_sum((v.x + v.y) + (v.z + v.w));   // blocksum
        }
        {   // row fold: this wave's 16 rows over 64 col-quads (LDS transpose)
            const int r = lane & 15, q = lane >> 4;
            float v = 0.f;
            #pragma unroll
            for (int k = 0; k < 16; ++k) v += part[g][q * 16 + k][r];
            v += __shfl_xor(v, 16, 64);
            v += __shfl_xor(v, 32, 64);
            float vp = __shfl_xor(v, 1, 64);          // partner row value
            if (lane < 16 && (lane & 1) == 0) {       // 8 b64 per wave
                u64* dst = rowF + (((size_t)(p * NBLK + b)) << 7) + 8 * g + (lane >> 1);
                st_b64(dst, packf2(v, vp));
            }
        }
        asm volatile("s_waitcnt vmcnt(0)" ::: "memory");  // own stores acked
        __syncthreads();                                  // A2: all drained
        if (t == 0)
            st_b64(pflag + ((size_t)(p * NBLK + b) << 3),
                   (tagv << 32) | (u64)__float_as_uint(bs));

        // ---- rendezvous: 256 dedicated pollers, one 64B-spaced flag each
        if (t < 256) {
            const u64* f = pflag + ((size_t)(p * NBLK + t) << 3);
            u64 u;
            while (((u = ld_b64(f)) >> 32) != tagv)
                __builtin_amdgcn_s_sleep(1);
            bsv[t] = lo32(u);
        }
        asm volatile("" ::: "memory");    // no hoisting loads above the poll
        __syncthreads();                  // B0: ALL flags observed; bsv ready

        // ---- phase B: gather 4 b64 (no wait needed), fold locally
        const int fcsrc = g * 16 + bj;    // col source block (bi'=g, bj)
        const int frsrc = bi * 16 + g;    // row source block (bi, bj'=g)
        {
            const u64* cp = colF + (((size_t)(p * NBLK + fcsrc)) << 7) + 2 * c;
            const u64* rp = rowF + (((size_t)(p * NBLK + frsrc)) << 7) + 2 * c;
            u64 c0 = ld_b64(cp), c1 = ld_b64(cp + 1);
            u64 r0 = ld_b64(rp), r1 = ld_b64(rp + 1);
            f32x4 cv, rv;
            cv.x = lo32(c0); cv.y = hi32(c0); cv.z = lo32(c1); cv.w = hi32(c1);
            rv.x = lo32(r0); rv.y = hi32(r0); rv.z = lo32(r1); rv.w = hi32(r1);
            cq[g][c]  = cv;               // cols 4c..4c+3 from peer g
            rq4[g][c] = rv;               // rows 4c..4c+3 from peer g
        }
        __syncthreads();                                  // B1: gathers in LDS
        if (g == 0) {            // colsum: fold 16 peer partials
            f32x4 v = cq[0][c];
            #pragma unroll
            for (int k = 1; k < 16; ++k) v += cq[k][c];
            colq[c] = v;
        } else if (g >= 4 && g < 8) {   // rowsum: 256 rows, conflict-free
            const int row = t - 256;
            const float* rqf = (const float*)rq4;
            float v = 0.f;
            #pragma unroll
            for (int k = 0; k < 16; ++k) v += rqf[k * 256 + row];
            rsum[row] = v;
        } else if (g == 8) {            // grand total (identical all blocks)
            float v = bsv[lane] + bsv[64 + lane] + bsv[128 + lane] + bsv[192 + lane];
            v = wave_reduce_sum(v);
            if (lane == 0) sG = v;
        }
        __syncthreads();                                  // B2

        const float cc0 = INV_N + sG * (INV_N * INV_N);
        const f32x4 csub = colq[c] * INV_N;
        #pragma unroll
        for (int r = 0; r < 16; ++r) {
            const float a = cc0 - rsum[g * 16 + r] * INV_N;
            x[r].x = fmaxf(x[r].x + a - csub.x, 0.f);
            x[r].y = fmaxf(x[r].y + a - csub.y, 0.f);
            x[r].z = fmaxf(x[r].z + a - csub.z, 0.f);
            x[r].w = fmaxf(x[r].w + a - csub.w, 0.f);
        }
        // next iteration's A1 __syncthreads protects LDS reuse
    }

    {   // final store (plain cached path)
        f32x4* xo = (f32x4*)Xout;
        const size_t base = (size_t)(bi * 256 + g * 16) * NV4 + (bj * 64 + c);
        #pragma unroll
        for (int r = 0; r < 16; ++r)
            xo[base + (size_t)r * NV4] = x[r];
    }
}

extern "C" void kernel_launch(void* const* d_in, const int* in_sizes, int n_in,
                              void* d_out, int out_size, void* d_ws, size_t ws_size,
                              hipStream_t stream)
{
    const float* X0 = (const float*)d_in[0];
    float* X = (float*)d_out;

    // ws: colF 512 KB | rowF 512 KB | pflag 32 KB   (~1.06 MB)
    u64* colF  = (u64*)d_ws;
    u64* rowF  = colF + 2 * NBLK * 128;
    u64* pflag = rowF + 2 * NBLK * 128;

    // Only flags need zeroing: data polls are exact-tag (tag in hi32 must
    // equal iter+1), so poisoned/stale words can never satisfy a poll.
    hipMemsetAsync((void*)pflag, 0, 2 * NBLK * 8 * sizeof(u64), stream);

    // 103.5 KB LDS + 16 waves -> exactly 1 block/CU; grid == CU count ->
    // all 256 blocks co-resident (spin-waits are deadlock-free).
    persist10<<<dim3(NBLK), dim3(1024), 0, stream>>>(X0, X, colF, rowF, pflag);
}